// Round 1
// baseline (89.314 us; speedup 1.0000x reference)
//
#include <hip/hip_runtime.h>

// SpikeEncoder: temporal one-hot coding.
//   lat[b,s,n] = int32( ((1 - clamp(f,0,1)) * 20) * scale[n] )   (trunc toward 0)
//   out[b,s,t,n] = (lat[b,s,n] == t) ? 1.0f : 0.0f
// Shapes: features [8,128,1024] f32, scale [1024] f32, out [8,128,20,1024] f32.
// Write-bound: ~84 MB out vs 4 MB in. One thread per 4 neurons; 20 coalesced
// float4 stores per thread (t-stride = N floats = 4 KB, lane-contiguous in n).

#define N_TIMESTEPS 20
#define N_NEURONS   1024
#define BATCH       8
#define SEQ_LEN     128

__global__ __launch_bounds__(256) void spike_encoder_kernel(
    const float4* __restrict__ feat,   // [B*S*N/4]
    const float4* __restrict__ scale,  // [N/4]
    float4* __restrict__ out)          // [B*S*T*N/4]
{
    const int idx = blockIdx.x * blockDim.x + threadIdx.x;  // over B*S*N/4
    const int n4  = idx & (N_NEURONS / 4 - 1);              // neuron-group index
    const int bs  = idx >> 8;                               // b*S + s  (N/4 == 256)

    const float4 f  = feat[idx];
    const float4 sc = scale[n4];

    // Match numpy fp32 rounding exactly: (1 - clamp(f)) round, *20 round,
    // *scale round, then trunc-toward-zero. __fsub_rn/__fmul_rn block FMA
    // contraction which could flip truncation at integer boundaries.
    const int lat_x = (int)__fmul_rn(__fmul_rn(__fsub_rn(1.0f, fminf(fmaxf(f.x, 0.0f), 1.0f)), 20.0f), sc.x);
    const int lat_y = (int)__fmul_rn(__fmul_rn(__fsub_rn(1.0f, fminf(fmaxf(f.y, 0.0f), 1.0f)), 20.0f), sc.y);
    const int lat_z = (int)__fmul_rn(__fmul_rn(__fsub_rn(1.0f, fminf(fmaxf(f.z, 0.0f), 1.0f)), 20.0f), sc.z);
    const int lat_w = (int)__fmul_rn(__fmul_rn(__fsub_rn(1.0f, fminf(fmaxf(f.w, 0.0f), 1.0f)), 20.0f), sc.w);

    // out[bs, t, n4]: base = bs * T * (N/4) + t * (N/4) + n4
    size_t base = (size_t)bs * (N_TIMESTEPS * (N_NEURONS / 4)) + n4;

#pragma unroll
    for (int t = 0; t < N_TIMESTEPS; ++t) {
        float4 v;
        v.x = (lat_x == t) ? 1.0f : 0.0f;
        v.y = (lat_y == t) ? 1.0f : 0.0f;
        v.z = (lat_z == t) ? 1.0f : 0.0f;
        v.w = (lat_w == t) ? 1.0f : 0.0f;
        out[base + (size_t)t * (N_NEURONS / 4)] = v;
    }
}

extern "C" void kernel_launch(void* const* d_in, const int* in_sizes, int n_in,
                              void* d_out, int out_size, void* d_ws, size_t ws_size,
                              hipStream_t stream) {
    const float4* feat  = (const float4*)d_in[0];  // [B,S,N] f32
    const float4* scale = (const float4*)d_in[1];  // [N] f32
    float4* out = (float4*)d_out;                  // [B,S,T,N] f32

    const int total4 = BATCH * SEQ_LEN * N_NEURONS / 4;  // 262144
    const int block = 256;
    const int grid = total4 / block;                     // 1024
    spike_encoder_kernel<<<grid, block, 0, stream>>>(feat, scale, out);
}